// Round 8
// baseline (265.737 us; speedup 1.0000x reference)
//
#include <hip/hip_runtime.h>
#include <math.h>

namespace {

constexpr int C_ = 3, T_ = 3000, F_ = 103, NB_ = 6;
constexpr int TT = 20;                       // 3000/20=150; TT*F=2060 %4==0
constexpr int BS[NB_]  = {1, 10, 20, 30, 40, 61};
constexpr int BNB[NB_] = {10, 11, 11, 11, 22, 16};
constexpr int BOF[NB_] = {0, 10, 21, 32, 43, 65};   // cumsum, total 81
constexpr int SPF = 81;                      // staged spec cols (bands span f=1..76)
constexpr int PLANE = T_ * F_;               // 309000
constexpr int SECP = 2064;                   // enh plane stride (2060 padded to x4)
constexpr int POOLN = 6320;                  // max(4860+1458, 3*2064)=6318 -> 6320

__device__ __forceinline__ float softplus_(float x) {
  return fmaxf(x, 0.0f) + log1pf(expf(-fabsf(x)));
}
__device__ __forceinline__ float sigmoid_(float z) {
  return 1.0f / (1.0f + __expf(-z));
}
__device__ __forceinline__ float gelu_(float x) {
  return x * sigmoid_(1.595769122f * x * (1.0f + 0.044715f * x * x));
}

__global__ __launch_bounds__(256, 4)
void sleepband_kernel(const float* __restrict__ spec,
                      const float* __restrict__ centers,
                      const float* __restrict__ widths,
                      const float* __restrict__ gains,
                      const float* __restrict__ align_w,
                      const float* __restrict__ align_b,
                      const float* __restrict__ fc1_w,
                      const float* __restrict__ fc1_b,
                      const float* __restrict__ fc2_w,
                      const float* __restrict__ fc2_b,
                      const float* __restrict__ band_gain,
                      const float* __restrict__ gate_w,
                      const float* __restrict__ gate_b,
                      const float* __restrict__ proj_w,
                      const float* __restrict__ proj_b,
                      const float* __restrict__ bn_gamma,
                      const float* __restrict__ bn_beta,
                      const float* __restrict__ bn_mean,
                      const float* __restrict__ bn_var,
                      float* __restrict__ out)
{
  // Pool: [Phase A] sSpec[C][TT][81] (4860) + sW (1458)  ||  [B2/final] sEnh[3][SECP]
  __shared__ __align__(16) float sPool[POOLN];
  __shared__ float sBand[TT][109];       // odd stride -> conflict-free
  __shared__ float sAw[54], sAb[18], sF1[108], sF1b[6], sF2[108], sF2b[18],
                   sBg[6], sGw[9], sGb[3], sPw[9], sPb[3];

  const int tid = threadIdx.x;
  const int t0  = blockIdx.x * TT;
  const int b   = blockIdx.y;

  float* sW = sPool + C_ * TT * SPF;     // gaussian weights, Phase A only

  // ---------------- stage spec band region (coalesced) ----------------
  const float* specB = spec + (size_t)b * C_ * PLANE;
  for (int li = tid; li < C_ * TT * SPF; li += 256) {
    int c   = li / (TT * SPF);
    int rem = li - c * (TT * SPF);
    int tt  = rem / SPF;
    int f   = rem - tt * SPF;
    sPool[li] = specB[(size_t)c * PLANE + (size_t)(t0 + tt) * F_ + f];
  }

  // ---------------- stage small params (folded proj/BN) ----------------
  if (tid < 54)  sAw[tid]  = align_w[tid];
  if (tid < 18)  sAb[tid]  = align_b[tid];
  if (tid < 108) sF1[tid]  = fc1_w[tid];
  if (tid < 6)   sF1b[tid] = fc1_b[tid];
  if (tid < 108) sF2[tid]  = fc2_w[tid];
  if (tid < 18)  sF2b[tid] = fc2_b[tid];
  if (tid < 6)   sBg[tid]  = band_gain[tid];
  if (tid < 9)   sGw[tid]  = gate_w[tid];
  if (tid < 3)   sGb[tid]  = gate_b[tid];
  if (tid < 9) {
    int d = tid / 3;
    float sc = bn_gamma[d] / sqrtf(bn_var[d] + 1e-5f);
    sPw[tid] = proj_w[tid] * sc;
  }
  if (tid < 3) {
    float sc = bn_gamma[tid] / sqrtf(bn_var[tid] + 1e-5f);
    sPb[tid] = (proj_b[tid] - bn_mean[tid]) * sc + bn_beta[tid];
  }

  // ---------------- gaussian filter bank (108 tasks, waves 2-3) ----------------
  if (tid >= 128 && tid < 128 + 108) {
    int q = tid - 128;
    int i = q / 18;                       // band
    int p = q - i * 18;                   // c*6+n ; flat centers idx == q
    int s = BS[i], nb = BNB[i];
    float mu = softplus_(centers[q]) + (float)s;
    mu = fminf(fmaxf(mu, (float)s), (float)(s + nb - 1));
    float sd = softplus_(widths[q]) + 0.001f;
    sd = fminf(fmaxf(sd, 0.5f), 2.0f * (float)nb / 6.0f);
    float sum = 0.0f;
    for (int f = 0; f < nb; ++f) {
      float d = ((float)f - mu) / sd;
      sum += __expf(-0.5f * d * d);
    }
    float sc = gains[q] / (sum + 1e-6f);
    float* wrow = &sW[BOF[i] * 18 + p * nb];
    for (int f = 0; f < nb; ++f) {
      float d = ((float)f - mu) / sd;
      wrow[f] = sc * __expf(-0.5f * d * d);
    }
  }
  __syncthreads();

  // ---------------- Phase A: filt, spec-row shared across n-triple ----------------
  // 2 waves: lane=(c,tt), wave ng handles n = 3ng..3ng+2. srow[f] read ONCE per
  // lane, applied to 3 accumulators; per-n accumulation order identical to ref.
  {
    const int ng  = tid >> 6;            // wave id 0..3
    const int idx = tid & 63;
    if (ng < 2 && idx < 60) {
      const int c  = idx / 20;
      const int tt = idx - c * 20;
      const int n0 = ng * 3;
      const float* srowb = &sPool[(c * TT + tt) * SPF];
      #pragma unroll
      for (int i = 0; i < NB_; ++i) {
        const int nb = BNB[i];
        const float* w0 = &sW[BOF[i] * 18 + (c * 6 + n0) * nb];
        const float* sr = srowb + BS[i];
        float a0 = 0.0f, a1 = 0.0f, a2 = 0.0f;
        #pragma unroll
        for (int f = 0; f < nb; ++f) {
          float s = sr[f];
          a0 += s * w0[f];
          a1 += s * w0[nb + f];
          a2 += s * w0[2 * nb + f];
        }
        sBand[tt][(i * 3 + c) * 6 + n0 + 0] = a0;
        sBand[tt][(i * 3 + c) * 6 + n0 + 1] = a1;
        sBand[tt][(i * 3 + c) * 6 + n0 + 2] = a2;
      }
    }
  }
  __syncthreads();

  // ---------------- Phase B: align + MLP + softmax + scale ----------------
  // 1 wave: lane=(n, tt-pair). Each weight loaded once, applied to both tt.
  if (tid < 60) {
    const int n   = tid / 10;
    const int tth = tid - n * 10;
    const int tA  = 2 * tth, tB = tA + 1;
    float al0[18], al1[18];
    #pragma unroll
    for (int i = 0; i < 6; ++i) {
      float f00 = sBand[tA][(i * 3 + 0) * 6 + n];
      float f01 = sBand[tA][(i * 3 + 1) * 6 + n];
      float f02 = sBand[tA][(i * 3 + 2) * 6 + n];
      float f10 = sBand[tB][(i * 3 + 0) * 6 + n];
      float f11 = sBand[tB][(i * 3 + 1) * 6 + n];
      float f12 = sBand[tB][(i * 3 + 2) * 6 + n];
      #pragma unroll
      for (int d = 0; d < 3; ++d) {
        float w0 = sAw[i * 9 + d * 3 + 0];
        float w1 = sAw[i * 9 + d * 3 + 1];
        float w2 = sAw[i * 9 + d * 3 + 2];
        float bb = sAb[i * 3 + d];
        al0[i * 3 + d] = w0 * f00 + w1 * f01 + w2 * f02 + bb;
        al1[i * 3 + d] = w0 * f10 + w1 * f11 + w2 * f12 + bb;
      }
    }
    float h0[6], h1[6];
    #pragma unroll
    for (int o = 0; o < 6; ++o) {
      float a0 = sF1b[o], a1 = sF1b[o];
      #pragma unroll
      for (int k = 0; k < 18; ++k) {
        float w = sF1[o * 18 + k];
        a0 += w * al0[k];
        a1 += w * al1[k];
      }
      h0[o] = gelu_(a0);
      h1[o] = gelu_(a1);
    }
    // per softmax column c: compute the 6 fc2 outputs {k=i*3+c} on the fly
    #pragma unroll
    for (int c = 0; c < 3; ++c) {
      float a0[6], a1[6];
      #pragma unroll
      for (int i = 0; i < 6; ++i) {
        const int k = i * 3 + c;
        float x0 = sF2b[k], x1 = sF2b[k];
        #pragma unroll
        for (int o = 0; o < 6; ++o) {
          float w = sF2[k * 6 + o];
          x0 += w * h0[o];
          x1 += w * h1[o];
        }
        a0[i] = x0; a1[i] = x1;
      }
      float m0 = a0[0], m1 = a1[0];
      #pragma unroll
      for (int i = 1; i < 6; ++i) { m0 = fmaxf(m0, a0[i]); m1 = fmaxf(m1, a1[i]); }
      float e0[6], e1[6], s0 = 0.0f, s1 = 0.0f;
      #pragma unroll
      for (int i = 0; i < 6; ++i) {
        e0[i] = __expf(a0[i] - m0); s0 += e0[i];
        e1[i] = __expf(a1[i] - m1); s1 += e1[i];
      }
      float i0 = 1.0f / s0, i1 = 1.0f / s1;
      #pragma unroll
      for (int i = 0; i < 6; ++i) {
        float bg = sBg[i];
        sBand[tA][(i * 3 + c) * 6 + n] = al0[i * 3 + c] * (e0[i] * i0) * bg;
        sBand[tB][(i * 3 + c) * 6 + n] = al1[i * 3 + c] * (e1[i] * i1) * bg;
      }
    }
  }
  __syncthreads();

  // ---------------- Phase B2: compile-time-tap upsample into dense enh ----------
  if (tid < C_ * TT) {
    const int c  = tid / TT;
    const int tt = tid - c * TT;
    float bnd[36];
    #pragma unroll
    for (int i = 0; i < 6; ++i)
      #pragma unroll
      for (int n = 0; n < 6; ++n)
        bnd[i * 6 + n] = sBand[tt][(i * 3 + c) * 6 + n];
    float* row = &sPool[c * SECP + tt * F_];
    row[0] = 0.0f;
    float carry = 0.0f;
    #pragma unroll
    for (int i = 0; i < NB_; ++i) {
      #pragma unroll
      for (int j = 0; j < BNB[i]; ++j) {
        float src = ((float)j + 0.5f) * 6.0f / (float)BNB[i] - 0.5f;
        src = src > 0.0f ? src : 0.0f;
        int   x0 = (int)src;
        int   x1 = (x0 < 5) ? x0 + 1 : 5;
        float wl = src - (float)x0;
        float v  = bnd[i * 6 + x0] * (1.0f - wl) + bnd[i * 6 + x1] * wl;
        if (j == 0) v += carry;
        if (i < NB_ - 1 && j == BNB[i] - 1) carry = v;
        else row[BS[i] + j] = v;
      }
    }
    #pragma unroll
    for (int f = 77; f < F_; ++f) row[f] = 0.0f;
  }
  __syncthreads();

  // ---------------- Final: flat float4 gate + folded proj + gelu ----------------
  float gw[9], pw[9], gb3[3], pb3[3];
  #pragma unroll
  for (int k = 0; k < 9; ++k) { gw[k] = sGw[k]; pw[k] = sPw[k]; }
  #pragma unroll
  for (int k = 0; k < 3; ++k) { gb3[k] = sGb[k]; pb3[k] = sPb[k]; }

  const float* sp0 = specB + (size_t)t0 * F_;
  float* outB = out + (size_t)b * C_ * PLANE + (size_t)t0 * F_;
  for (int e4 = tid; e4 < (TT * F_) / 4 + 1; e4 += 256) {
    if (e4 >= (TT * F_ + 3) / 4) break;
    const int e = e4 * 4;
    if (e >= TT * F_) break;
    const float4 sA = *(const float4*)(sp0 + e);
    const float4 sB = *(const float4*)(sp0 + PLANE + e);
    const float4 sC = *(const float4*)(sp0 + 2 * PLANE + e);
    const float4 eA = *(const float4*)&sPool[0 * SECP + e];
    const float4 eB = *(const float4*)&sPool[1 * SECP + e];
    const float4 eC = *(const float4*)&sPool[2 * SECP + e];
    float4 oA, oB, oC;
    const float* sAp = (const float*)&sA; const float* sBp = (const float*)&sB;
    const float* sCp = (const float*)&sC;
    const float* eAp = (const float*)&eA; const float* eBp = (const float*)&eB;
    const float* eCp = (const float*)&eC;
    float* oAp = (float*)&oA; float* oBp = (float*)&oB; float* oCp = (float*)&oC;
    #pragma unroll
    for (int j = 0; j < 4; ++j) {
      float sv0 = sAp[j], sv1 = sBp[j], sv2 = sCp[j];
      float r0 = eAp[j] - sv0, r1 = eBp[j] - sv1, r2 = eCp[j] - sv2;
      float e20 = sv0 + sigmoid_(gw[0] * r0 + gw[1] * r1 + gw[2] * r2 + gb3[0]) * r0;
      float e21 = sv1 + sigmoid_(gw[3] * r0 + gw[4] * r1 + gw[5] * r2 + gb3[1]) * r1;
      float e22 = sv2 + sigmoid_(gw[6] * r0 + gw[7] * r1 + gw[8] * r2 + gb3[2]) * r2;
      float y0 = pw[0] * e20 + pw[1] * e21 + pw[2] * e22 + pb3[0];
      float y1 = pw[3] * e20 + pw[4] * e21 + pw[5] * e22 + pb3[1];
      float y2 = pw[6] * e20 + pw[7] * e21 + pw[8] * e22 + pb3[2];
      oAp[j] = gelu_(y0); oBp[j] = gelu_(y1); oCp[j] = gelu_(y2);
    }
    *(float4*)(outB + e) = oA;
    *(float4*)(outB + PLANE + e) = oB;
    *(float4*)(outB + 2 * PLANE + e) = oC;
  }
}

} // namespace

extern "C" void kernel_launch(void* const* d_in, const int* in_sizes, int n_in,
                              void* d_out, int out_size, void* d_ws, size_t ws_size,
                              hipStream_t stream) {
  (void)n_in; (void)out_size; (void)d_ws; (void)ws_size;
  const int B = in_sizes[0] / (C_ * T_ * F_);   // 64
  dim3 grid(T_ / TT, B);                        // (150, 64)
  sleepband_kernel<<<grid, 256, 0, stream>>>(
      (const float*)d_in[0],  (const float*)d_in[1],  (const float*)d_in[2],
      (const float*)d_in[3],  (const float*)d_in[4],  (const float*)d_in[5],
      (const float*)d_in[6],  (const float*)d_in[7],  (const float*)d_in[8],
      (const float*)d_in[9],  (const float*)d_in[10], (const float*)d_in[11],
      (const float*)d_in[12], (const float*)d_in[13], (const float*)d_in[14],
      (const float*)d_in[15], (const float*)d_in[16], (const float*)d_in[17],
      (const float*)d_in[18], (float*)d_out);
}